// Round 2
// baseline (2654.600 us; speedup 1.0000x reference)
//
#include <hip/hip_runtime.h>
#include <hip/hip_bf16.h>

typedef __hip_bfloat16 bf16;
typedef unsigned short u16;

#define N_NODES 100000
#define N_EDGES 1600000
#define F_IN 64
#define N_REL 8
#define N_GRAPH 256
#define N_HEAD 4
#define HC 128  // H*C

__device__ __forceinline__ float lrelu(float x, float s) { return x >= 0.f ? x : s * x; }
// order-preserving float<->uint map for atomicMax on signed floats
__device__ __forceinline__ unsigned fenc(float f) {
  unsigned b = __float_as_uint(f);
  return (b & 0x80000000u) ? ~b : (b | 0x80000000u);
}
__device__ __forceinline__ float fdec(unsigned u) {
  float v = __uint_as_float((u & 0x80000000u) ? (u & 0x7fffffffu) : ~u);
  // sanitize: kill NaN/Inf from any unwritten sentinel (finite wrongness > NaN)
  return fmaxf(fminf(v, 3e38f), -3e38f);
}
__device__ __forceinline__ float bf2f(bf16 v) { return __bfloat162float(v); }
__device__ __forceinline__ bf16 f2bf(float v) { return __float2bfloat16(v); }

// dtype-adaptive load: BF=true -> array is bf16; BF=false -> array is fp32
template<bool BF> __device__ __forceinline__ float ldf(const void* p, size_t i) {
  if (BF) { u16 v = ((const u16*)p)[i]; return __uint_as_float(((unsigned)v) << 16); }
  else    { return ((const float*)p)[i]; }
}

// ---- dtype probe: bf16 normal data has exponent field clustered near 127 ----
__global__ void k_probe(const u16* __restrict__ xr, int* __restrict__ flag) {
  int t = threadIdx.x;
  int c = 0;
  for (int i = t; i < 1024; i += 256) {
    unsigned e = (xr[i] >> 7) & 0xFFu;
    if (e >= 100u && e <= 140u) c++;
  }
  __shared__ int sc[256];
  sc[t] = c;
  __syncthreads();
  for (int s = 128; s; s >>= 1) { if (t < s) sc[t] += sc[t + s]; __syncthreads(); }
  if (t == 0) *flag = (sc[0] >= 800) ? 1 : 0;  // bf16 ~1024 hits, fp32 ~594
}

// ---- GAT: h = x @ gat_w ; a_src/a_dst = rowwise head-dot with att vectors ----
template<bool BF>
__device__ __forceinline__ void gat_h_body(const void* x, const void* w, const void* att_s,
                                           const void* att_d, bf16* __restrict__ h,
                                           float* __restrict__ a_src, float* __restrict__ a_dst) {
  int n = blockIdx.x;
  int j = threadIdx.x;  // 128 threads = one output row
  __shared__ float xs[F_IN];
  if (j < F_IN) xs[j] = ldf<BF>(x, (size_t)n * F_IN + j);
  __syncthreads();
  float acc = 0.f;
#pragma unroll
  for (int k = 0; k < F_IN; ++k) acc += xs[k] * ldf<BF>(w, (size_t)k * HC + j);
  h[(size_t)n * HC + j] = f2bf(acc);
  float ps = acc * ldf<BF>(att_s, j);
  float pd = acc * ldf<BF>(att_d, j);
#pragma unroll
  for (int off = 16; off > 0; off >>= 1) {
    ps += __shfl_down(ps, off, 32);
    pd += __shfl_down(pd, off, 32);
  }
  if ((j & 31) == 0) {
    a_src[n * N_HEAD + (j >> 5)] = ps;
    a_dst[n * N_HEAD + (j >> 5)] = pd;
  }
}
__global__ void k_gat_h(const void* x, const void* w, const void* att_s, const void* att_d,
                        bf16* h, float* a_src, float* a_dst, const int* flag) {
  if (__builtin_amdgcn_readfirstlane(*flag)) gat_h_body<true>(x, w, att_s, att_d, h, a_src, a_dst);
  else gat_h_body<false>(x, w, att_s, att_d, h, a_src, a_dst);
}

// ---- edge pass 1: segment-max of leaky(e) into m (encoded uint) + (dst,rel) counts ----
__global__ void k_edge_pre(const int* __restrict__ ei, const int* __restrict__ etype,
                           const float* __restrict__ a_src, const float* __restrict__ a_dst,
                           unsigned* __restrict__ m, int* __restrict__ cnt) {
  int e = blockIdx.x * blockDim.x + threadIdx.x;
  if (e >= N_EDGES) return;
  int sn = ei[e], d = ei[N_EDGES + e], t = etype[e];
  atomicAdd(&cnt[d * N_REL + t], 1);
  const float4 as = *(const float4*)&a_src[sn * 4];
  const float4 ad = *(const float4*)&a_dst[d * 4];
  atomicMax(&m[d * 4 + 0], fenc(lrelu(as.x + ad.x, 0.2f)));
  atomicMax(&m[d * 4 + 1], fenc(lrelu(as.y + ad.y, 0.2f)));
  atomicMax(&m[d * 4 + 2], fenc(lrelu(as.z + ad.z, 0.2f)));
  atomicMax(&m[d * 4 + 3], fenc(lrelu(as.w + ad.w, 0.2f)));
}

// ---- edge pass 2: p = exp(e - m[dst]), s = segment-sum ----
__global__ void k_edge_p(const int* __restrict__ ei,
                         const float* __restrict__ a_src, const float* __restrict__ a_dst,
                         const unsigned* __restrict__ m, float* __restrict__ p,
                         float* __restrict__ s) {
  int e = blockIdx.x * blockDim.x + threadIdx.x;
  if (e >= N_EDGES) return;
  int sn = ei[e], d = ei[N_EDGES + e];
  const float4 as = *(const float4*)&a_src[sn * 4];
  const float4 ad = *(const float4*)&a_dst[d * 4];
  float4 pv;
  pv.x = __expf(lrelu(as.x + ad.x, 0.2f) - fdec(m[d * 4 + 0]));
  pv.y = __expf(lrelu(as.y + ad.y, 0.2f) - fdec(m[d * 4 + 1]));
  pv.z = __expf(lrelu(as.z + ad.z, 0.2f) - fdec(m[d * 4 + 2]));
  pv.w = __expf(lrelu(as.w + ad.w, 0.2f) - fdec(m[d * 4 + 3]));
  *(float4*)&p[(size_t)e * 4] = pv;
  atomicAdd(&s[d * 4 + 0], pv.x);
  atomicAdd(&s[d * 4 + 1], pv.y);
  atomicAdd(&s[d * 4 + 2], pv.z);
  atomicAdd(&s[d * 4 + 3], pv.w);
}

// ---- edge pass 3: out[dst] += h[src] * alpha ----
__global__ void k_edge_msg(const int* __restrict__ ei, const float* __restrict__ p,
                           const float* __restrict__ s, const bf16* __restrict__ h,
                           float* __restrict__ outacc) {
  int tid = threadIdx.x;
  int e = blockIdx.x * 2 + (tid >> 7);
  if (e >= N_EDGES) return;
  int j = tid & 127, head = j >> 5;
  int sn = ei[e], d = ei[N_EDGES + e];
  float den = fmaxf(s[d * 4 + head], 1e-30f);
  float alpha = p[(size_t)e * 4 + head] / den;
  float v = bf2f(h[(size_t)sn * HC + j]) * alpha;
  atomicAdd(&outacc[(size_t)d * HC + j], v);
}

// ---- GAT epilogue: bias+lrelu, dense1+lrelu, graph segment-max; also node counts ----
template<bool BF>
__device__ __forceinline__ void gat_out_body(const float* __restrict__ outacc, const void* gbias,
                                             const void* d1w, const void* d1b,
                                             const int* __restrict__ batch,
                                             unsigned* __restrict__ gmax, int* __restrict__ npg) {
  int n = blockIdx.x, j = threadIdx.x;
  __shared__ float os[HC];
  float o = outacc[(size_t)n * HC + j] + ldf<BF>(gbias, j);
  os[j] = lrelu(o, 0.01f);
  __syncthreads();
  if (j < 16) {
    float acc = ldf<BF>(d1b, j);
#pragma unroll
    for (int k = 0; k < HC; ++k) acc += os[k] * ldf<BF>(d1w, (size_t)k * 16 + j);
    acc = lrelu(acc, 0.01f);
    atomicMax(&gmax[batch[n] * 16 + j], fenc(acc));
  }
  if (j == 0) atomicAdd(&npg[batch[n]], 1);
}
__global__ void k_gat_out(const float* outacc, const void* gbias, const void* d1w,
                          const void* d1b, const int* batch, unsigned* gmax, int* npg,
                          const int* flag) {
  if (__builtin_amdgcn_readfirstlane(*flag)) gat_out_body<true>(outacc, gbias, d1w, d1b, batch, gmax, npg);
  else gat_out_body<false>(outacc, gbias, d1w, d1b, batch, gmax, npg);
}

// ---- RGCN1: xw1[r,n,32] = x[n] @ rw1[r] ----
template<bool BF>
__device__ __forceinline__ void xw1_body(const void* x, const void* rw1, bf16* __restrict__ xw1) {
  __shared__ float xs[8][F_IN];
  int tid = threadIdx.x;
  int n0 = blockIdx.x * 8;
  for (int i = tid; i < 8 * F_IN; i += 256) {
    int nn = n0 + (i >> 6);
    xs[i >> 6][i & 63] = (nn < N_NODES) ? ldf<BF>(x, (size_t)nn * F_IN + (i & 63)) : 0.f;
  }
  __syncthreads();
  int nl = tid >> 5, c = tid & 31;
  int n = n0 + nl, r = blockIdx.y;
  float acc = 0.f;
#pragma unroll
  for (int k = 0; k < F_IN; ++k) acc += xs[nl][k] * ldf<BF>(rw1, (size_t)(r * F_IN + k) * 32 + c);
  if (n < N_NODES) xw1[((size_t)r * N_NODES + n) * 32 + c] = f2bf(acc);
}
__global__ void k_xw1(const void* x, const void* rw1, bf16* xw1, const int* flag) {
  if (__builtin_amdgcn_readfirstlane(*flag)) xw1_body<true>(x, rw1, xw1);
  else xw1_body<false>(x, rw1, xw1);
}

// ---- RGCN1 edge scatter: agg[dst] += xw1[et,src] / cnt[dst,et] ----
__global__ void k_redge1(const int* __restrict__ ei, const int* __restrict__ etype,
                         const int* __restrict__ cnt, const bf16* __restrict__ xw1,
                         float* __restrict__ agg) {
  int idx = blockIdx.x * blockDim.x + threadIdx.x;  // E*32 = 51.2M < 2^31
  int e = idx >> 5, c = idx & 31;
  if (e >= N_EDGES) return;
  int sn = ei[e], d = ei[N_EDGES + e], t = etype[e];
  int cn = cnt[d * N_REL + t]; if (cn < 1) cn = 1;
  float inv = 1.f / (float)cn;
  float v = bf2f(xw1[((size_t)t * N_NODES + sn) * 32 + c]) * inv;
  atomicAdd(&agg[(size_t)d * 32 + c], v);
}

// ---- z1 = relu(agg + x @ root1 + rb1) ----
template<bool BF>
__device__ __forceinline__ void z1_body(const void* x, const void* root1, const void* rb1,
                                        const float* __restrict__ agg, float* __restrict__ z1) {
  __shared__ float xs[8][F_IN];
  int tid = threadIdx.x;
  int n0 = blockIdx.x * 8;
  for (int i = tid; i < 8 * F_IN; i += 256) {
    int nn = n0 + (i >> 6);
    xs[i >> 6][i & 63] = (nn < N_NODES) ? ldf<BF>(x, (size_t)nn * F_IN + (i & 63)) : 0.f;
  }
  __syncthreads();
  int nl = tid >> 5, c = tid & 31;
  int n = n0 + nl;
  float acc = 0.f;
#pragma unroll
  for (int k = 0; k < F_IN; ++k) acc += xs[nl][k] * ldf<BF>(root1, (size_t)k * 32 + c);
  if (n < N_NODES) {
    acc += agg[(size_t)n * 32 + c] + ldf<BF>(rb1, c);
    z1[(size_t)n * 32 + c] = fmaxf(acc, 0.f);
  }
}
__global__ void k_z1(const void* x, const void* root1, const void* rb1, const float* agg,
                     float* z1, const int* flag) {
  if (__builtin_amdgcn_readfirstlane(*flag)) z1_body<true>(x, root1, rb1, agg, z1);
  else z1_body<false>(x, root1, rb1, agg, z1);
}

// ---- RGCN2: zw2[r,n,16] = z1[n] @ rw2[r] ----
template<bool BF>
__device__ __forceinline__ void zw2_body(const float* __restrict__ z1, const void* rw2,
                                         bf16* __restrict__ zw2) {
  __shared__ float zs[16][32];
  int tid = threadIdx.x;
  int n0 = blockIdx.x * 16;
  for (int i = tid; i < 16 * 32; i += 256) {
    int nn = n0 + (i >> 5);
    zs[i >> 5][i & 31] = (nn < N_NODES) ? z1[(size_t)nn * 32 + (i & 31)] : 0.f;
  }
  __syncthreads();
  int nl = tid >> 4, c = tid & 15;
  int n = n0 + nl, r = blockIdx.y;
  float acc = 0.f;
#pragma unroll
  for (int k = 0; k < 32; ++k) acc += zs[nl][k] * ldf<BF>(rw2, (size_t)(r * 32 + k) * 16 + c);
  if (n < N_NODES) zw2[((size_t)r * N_NODES + n) * 16 + c] = f2bf(acc);
}
__global__ void k_zw2(const float* z1, const void* rw2, bf16* zw2, const int* flag) {
  if (__builtin_amdgcn_readfirstlane(*flag)) zw2_body<true>(z1, rw2, zw2);
  else zw2_body<false>(z1, rw2, zw2);
}

// ---- RGCN2 edge scatter ----
__global__ void k_redge2(const int* __restrict__ ei, const int* __restrict__ etype,
                         const int* __restrict__ cnt, const bf16* __restrict__ zw2,
                         float* __restrict__ agg2) {
  int idx = blockIdx.x * blockDim.x + threadIdx.x;  // E*16 = 25.6M
  int e = idx >> 4, c = idx & 15;
  if (e >= N_EDGES) return;
  int sn = ei[e], d = ei[N_EDGES + e], t = etype[e];
  int cn = cnt[d * N_REL + t]; if (cn < 1) cn = 1;
  float inv = 1.f / (float)cn;
  float v = bf2f(zw2[((size_t)t * N_NODES + sn) * 16 + c]) * inv;
  atomicAdd(&agg2[(size_t)d * 16 + c], v);
}

// ---- z2 = relu(agg2 + z1 @ root2 + rb2); gsum[graph] += z2 ----
template<bool BF>
__device__ __forceinline__ void z2_body(const float* __restrict__ z1, const void* root2,
                                        const void* rb2, const float* __restrict__ agg2,
                                        const int* __restrict__ batch, float* __restrict__ gsum) {
  __shared__ float zs[16][32];
  int tid = threadIdx.x;
  int n0 = blockIdx.x * 16;
  for (int i = tid; i < 16 * 32; i += 256) {
    int nn = n0 + (i >> 5);
    zs[i >> 5][i & 31] = (nn < N_NODES) ? z1[(size_t)nn * 32 + (i & 31)] : 0.f;
  }
  __syncthreads();
  int nl = tid >> 4, c = tid & 15;
  int n = n0 + nl;
  if (n >= N_NODES) return;
  float acc = 0.f;
#pragma unroll
  for (int k = 0; k < 32; ++k) acc += zs[nl][k] * ldf<BF>(root2, (size_t)k * 16 + c);
  acc += agg2[(size_t)n * 16 + c] + ldf<BF>(rb2, c);
  acc = fmaxf(acc, 0.f);
  atomicAdd(&gsum[batch[n] * 16 + c], acc);
}
__global__ void k_z2(const float* z1, const void* root2, const void* rb2, const float* agg2,
                     const int* batch, float* gsum, const int* flag) {
  if (__builtin_amdgcn_readfirstlane(*flag)) z2_body<true>(z1, root2, rb2, agg2, batch, gsum);
  else z2_body<false>(z1, root2, rb2, agg2, batch, gsum);
}

// ---- final: zc = [gmax, gmean] @ dense_w + dense_b ----
template<bool BF>
__device__ __forceinline__ void final_body(const unsigned* __restrict__ gmax,
                                           const float* __restrict__ gsum,
                                           const int* __restrict__ npg, const void* dw,
                                           const void* db, void* out) {
  int g = threadIdx.x;
  if (g >= N_GRAPH) return;
  float acc = ldf<BF>(db, 0);
  int np = npg[g]; if (np < 1) np = 1;
  float inv = 1.f / (float)np;
#pragma unroll
  for (int c = 0; c < 16; ++c) {
    acc += fdec(gmax[g * 16 + c]) * ldf<BF>(dw, c);
    acc += (gsum[g * 16 + c] * inv) * ldf<BF>(dw, 16 + c);
  }
  if (BF) ((bf16*)out)[g] = f2bf(acc);
  else ((float*)out)[g] = acc;
}
__global__ void k_final(const unsigned* gmax, const float* gsum, const int* npg,
                        const void* dw, const void* db, void* out, const int* flag) {
  if (__builtin_amdgcn_readfirstlane(*flag)) final_body<true>(gmax, gsum, npg, dw, db, out);
  else final_body<false>(gmax, gsum, npg, dw, db, out);
}

extern "C" void kernel_launch(void* const* d_in, const int* in_sizes, int n_in,
                              void* d_out, int out_size, void* d_ws, size_t ws_size,
                              hipStream_t stream) {
  const void* x        = d_in[0];
  const int*  ei       = (const int*)d_in[1];
  const int*  etype    = (const int*)d_in[2];
  const int*  batch    = (const int*)d_in[3];
  const void* gat_w    = d_in[4];
  const void* att_src  = d_in[5];
  const void* att_dst  = d_in[6];
  const void* gat_bias = d_in[7];
  const void* d1w      = d_in[8];
  const void* d1b      = d_in[9];
  const void* rw1      = d_in[10];
  const void* root1    = d_in[11];
  const void* rb1      = d_in[12];
  const void* rw2      = d_in[13];
  const void* root2    = d_in[14];
  const void* rb2      = d_in[15];
  const void* dw       = d_in[16];
  const void* db       = d_in[17];

  // ---- workspace layout (phase-aliased regions), ~131.3 MB ----
  char* ws = (char*)d_ws;
  const size_t o_h    = 0;            // bf16 N*128            (25.6 MB)  GAT phase
  const size_t o_p    = 25600000;     // f32  E*4              (25.6 MB)  GAT phase
  const size_t o_xw1  = 0;            // bf16 R*N*32           (51.2 MB)  RGCN1, aliases h+p
  const size_t o_out  = 51200000;     // f32  N*128            (51.2 MB)  GAT accumulate
  const size_t o_zw2  = 51200000;     // bf16 R*N*16           (25.6 MB)  RGCN2, aliases out
  const size_t o_asrc = 102400000;    // f32  N*4
  const size_t o_adst = 104000000;    // f32  N*4
  const size_t o_m    = 105600000;    // u32  N*4
  const size_t o_s    = 107200000;    // f32  N*4
  const size_t o_z1   = 102400000;    // f32  N*32 (12.8 MB), aliases asrc..s (dead by then)
  const size_t o_cnt  = 115200000;    // i32  N*8              (3.2 MB)
  const size_t o_agg  = 118400000;    // f32  N*32 (12.8 MB); agg2 f32 N*16 aliases
  const size_t o_gmax = 131200000;    // u32  G*16
  const size_t o_gsum = 131216384;    // f32  G*16
  const size_t o_npg  = 131232768;    // i32  G
  const size_t o_flag = 131233792;    // i32  dtype flag
  const size_t total  = 131233796;
  if (ws_size < total) return;

  float*    h_a    = (float*)(ws + o_out);
  bf16*     h_bf   = (bf16*)(ws + o_h);
  float*    p_p    = (float*)(ws + o_p);
  bf16*     xw1    = (bf16*)(ws + o_xw1);
  bf16*     zw2    = (bf16*)(ws + o_zw2);
  float*    a_src  = (float*)(ws + o_asrc);
  float*    a_dst  = (float*)(ws + o_adst);
  unsigned* m      = (unsigned*)(ws + o_m);
  float*    sden   = (float*)(ws + o_s);
  float*    z1     = (float*)(ws + o_z1);
  int*      cnt    = (int*)(ws + o_cnt);
  float*    agg    = (float*)(ws + o_agg);
  float*    agg2   = (float*)(ws + o_agg);
  unsigned* gmax   = (unsigned*)(ws + o_gmax);
  float*    gsum   = (float*)(ws + o_gsum);
  int*      npg    = (int*)(ws + o_npg);
  int*      flag   = (int*)(ws + o_flag);

  // dtype probe first
  k_probe<<<1, 256, 0, stream>>>((const u16*)x, flag);

  // zero-init (ws is poisoned 0xAA before every call)
  hipMemsetAsync(ws + o_out, 0, 51200000, stream);           // GAT accumulator
  hipMemsetAsync(ws + o_m, 0, 3200000, stream);              // m (enc 0 = -inf) + s
  hipMemsetAsync(ws + o_cnt, 0, 3200000 + 12800000, stream); // cnt + agg
  hipMemsetAsync(ws + o_gmax, 0, 33792, stream);             // gmax(enc) + gsum + npg

  // GAT branch
  k_gat_h<<<N_NODES, 128, 0, stream>>>(x, gat_w, att_src, att_dst, h_bf, a_src, a_dst, flag);
  k_edge_pre<<<(N_EDGES + 255) / 256, 256, 0, stream>>>(ei, etype, a_src, a_dst, m, cnt);
  k_edge_p<<<(N_EDGES + 255) / 256, 256, 0, stream>>>(ei, a_src, a_dst, m, p_p, sden);
  k_edge_msg<<<N_EDGES / 2, 256, 0, stream>>>(ei, p_p, sden, h_bf, h_a);
  k_gat_out<<<N_NODES, 128, 0, stream>>>(h_a, gat_bias, d1w, d1b, batch, gmax, npg, flag);

  // RGCN layer 1
  k_xw1<<<dim3((N_NODES + 7) / 8, N_REL), 256, 0, stream>>>(x, rw1, xw1, flag);
  k_redge1<<<(N_EDGES * 32) / 256, 256, 0, stream>>>(ei, etype, cnt, xw1, agg);
  k_z1<<<(N_NODES + 7) / 8, 256, 0, stream>>>(x, root1, rb1, agg, z1, flag);

  // RGCN layer 2 (agg2 aliases agg — re-zero now that agg is consumed)
  hipMemsetAsync(ws + o_agg, 0, 6400000, stream);
  k_zw2<<<dim3((N_NODES + 15) / 16, N_REL), 256, 0, stream>>>(z1, rw2, zw2, flag);
  k_redge2<<<(N_EDGES * 16) / 256, 256, 0, stream>>>(ei, etype, cnt, zw2, agg2);
  k_z2<<<(N_NODES + 15) / 16, 256, 0, stream>>>(z1, root2, rb2, agg2, batch, gsum, flag);

  // fuse
  k_final<<<1, 256, 0, stream>>>(gmax, gsum, npg, dw, db, d_out, flag);
}

// Round 3
// 1435.266 us; speedup vs baseline: 1.8496x; 1.8496x over previous
//
#include <hip/hip_runtime.h>
#include <hip/hip_bf16.h>

typedef __hip_bfloat16 bf16;
typedef unsigned short u16;

#define N_NODES 100000
#define N_EDGES 1600000
#define F_IN 64
#define N_REL 8
#define N_GRAPH 256
#define N_HEAD 4
#define HC 128          // H*C
#define NBLK_SCAN 391   // ceil(100000/256)

__device__ __forceinline__ float lrelu(float x, float s) { return x >= 0.f ? x : s * x; }
__device__ __forceinline__ unsigned fenc(float f) {
  unsigned b = __float_as_uint(f);
  return (b & 0x80000000u) ? ~b : (b | 0x80000000u);
}
__device__ __forceinline__ float fdec(unsigned u) {
  float v = __uint_as_float((u & 0x80000000u) ? (u & 0x7fffffffu) : ~u);
  return fmaxf(fminf(v, 3e38f), -3e38f);
}
__device__ __forceinline__ float bf2f(bf16 v) { return __bfloat162float(v); }
__device__ __forceinline__ bf16 f2bf(float v) { return __float2bfloat16(v); }

// dtype-adaptive load: BF=true -> bf16 array; BF=false -> fp32 array
template<bool BF> __device__ __forceinline__ float ldf(const void* p, size_t i) {
  if (BF) { u16 v = ((const u16*)p)[i]; return __uint_as_float(((unsigned)v) << 16); }
  else    { return ((const float*)p)[i]; }
}

// ---- dtype probe ----
__global__ void k_probe(const u16* __restrict__ xr, int* __restrict__ flag) {
  int t = threadIdx.x;
  int c = 0;
  for (int i = t; i < 1024; i += 256) {
    unsigned e = (xr[i] >> 7) & 0xFFu;
    if (e >= 100u && e <= 140u) c++;
  }
  __shared__ int sc[256];
  sc[t] = c;
  __syncthreads();
  for (int s = 128; s; s >>= 1) { if (t < s) sc[t] += sc[t + s]; __syncthreads(); }
  if (t == 0) *flag = (sc[0] >= 800) ? 1 : 0;
}

// ---- GAT: h = x @ gat_w ; a_src/a_dst rowwise head-dots ----
template<bool BF>
__device__ __forceinline__ void gat_h_body(const void* x, const void* w, const void* att_s,
                                           const void* att_d, bf16* __restrict__ h,
                                           float* __restrict__ a_src, float* __restrict__ a_dst) {
  int n = blockIdx.x, j = threadIdx.x;
  __shared__ float xs[F_IN];
  if (j < F_IN) xs[j] = ldf<BF>(x, (size_t)n * F_IN + j);
  __syncthreads();
  float acc = 0.f;
#pragma unroll
  for (int k = 0; k < F_IN; ++k) acc += xs[k] * ldf<BF>(w, (size_t)k * HC + j);
  h[(size_t)n * HC + j] = f2bf(acc);
  float ps = acc * ldf<BF>(att_s, j);
  float pd = acc * ldf<BF>(att_d, j);
#pragma unroll
  for (int off = 16; off > 0; off >>= 1) {
    ps += __shfl_down(ps, off, 32);
    pd += __shfl_down(pd, off, 32);
  }
  if ((j & 31) == 0) {
    a_src[n * N_HEAD + (j >> 5)] = ps;
    a_dst[n * N_HEAD + (j >> 5)] = pd;
  }
}
__global__ void k_gat_h(const void* x, const void* w, const void* att_s, const void* att_d,
                        bf16* h, float* a_src, float* a_dst, const int* flag) {
  if (__builtin_amdgcn_readfirstlane(*flag)) gat_h_body<true>(x, w, att_s, att_d, h, a_src, a_dst);
  else gat_h_body<false>(x, w, att_s, att_d, h, a_src, a_dst);
}

// ---- CSR build: histogram ----
__global__ void k_hist(const int* __restrict__ ei, const int* __restrict__ etype,
                       int* __restrict__ deg, int* __restrict__ cnt) {
  int e = blockIdx.x * 256 + threadIdx.x;
  if (e >= N_EDGES) return;
  int d = ei[N_EDGES + e], t = etype[e];
  atomicAdd(&deg[d], 1);
  atomicAdd(&cnt[d * N_REL + t], 1);
}

// ---- 2-level exclusive scan over deg[100000] -> rowptr ----
__global__ void k_scan_a(const int* __restrict__ deg, int* __restrict__ rowptr,
                         int* __restrict__ scanblk) {
  __shared__ int buf[256];
  int tid = threadIdx.x;
  int i = blockIdx.x * 256 + tid;
  int v = (i < N_NODES) ? deg[i] : 0;
  buf[tid] = v;
  __syncthreads();
  for (int st = 1; st < 256; st <<= 1) {
    int t = buf[tid];
    int a = (tid >= st) ? buf[tid - st] : 0;
    __syncthreads();
    buf[tid] = t + a;
    __syncthreads();
  }
  if (i < N_NODES) rowptr[i] = buf[tid] - v;           // block-local exclusive
  if (tid == 255) scanblk[blockIdx.x] = buf[255];       // block total
}
__global__ void k_scan_b(int* __restrict__ scanblk) {
  __shared__ int buf[512];
  int tid = threadIdx.x;
  int v = (tid < NBLK_SCAN) ? scanblk[tid] : 0;
  buf[tid] = v;
  __syncthreads();
  for (int st = 1; st < 512; st <<= 1) {
    int t = buf[tid];
    int a = (tid >= st) ? buf[tid - st] : 0;
    __syncthreads();
    buf[tid] = t + a;
    __syncthreads();
  }
  if (tid < NBLK_SCAN) scanblk[tid] = buf[tid] - v;     // exclusive
}
__global__ void k_scan_c(int* __restrict__ rowptr, int* __restrict__ wp,
                         const int* __restrict__ scanblk) {
  int i = blockIdx.x * 256 + threadIdx.x;
  if (i < N_NODES) {
    int val = rowptr[i] + scanblk[blockIdx.x];
    rowptr[i] = val;
    wp[i] = val;
  } else if (i == N_NODES) {
    rowptr[N_NODES] = N_EDGES;
  }
}

// ---- scatter edges into CSR order; also compute+store attention logits ----
__global__ void k_scatter(const int* __restrict__ ei, const int* __restrict__ etype,
                          const float* __restrict__ a_src, const float* __restrict__ a_dst,
                          int* __restrict__ wp, unsigned* __restrict__ csr,
                          float4* __restrict__ p_logit) {
  int e = blockIdx.x * 256 + threadIdx.x;
  if (e >= N_EDGES) return;
  int sn = ei[e], d = ei[N_EDGES + e], t = etype[e];
  int pos = atomicAdd(&wp[d], 1);
  csr[pos] = (unsigned)sn | ((unsigned)t << 20);
  const float4 as = *(const float4*)&a_src[sn * 4];
  const float4 ad = *(const float4*)&a_dst[d * 4];
  float4 lg;
  lg.x = lrelu(as.x + ad.x, 0.2f);
  lg.y = lrelu(as.y + ad.y, 0.2f);
  lg.z = lrelu(as.z + ad.z, 0.2f);
  lg.w = lrelu(as.w + ad.w, 0.2f);
  p_logit[pos] = lg;
}

// ---- GAT aggregate (gather, no atomics) + bias + lrelu + dense1 + graph-max ----
template<bool BF>
__device__ __forceinline__ void gat_agg_body(const int* __restrict__ rowptr,
                                             const unsigned* __restrict__ csr,
                                             const float* __restrict__ p_logit,
                                             const bf16* __restrict__ h, const void* gbias,
                                             const void* d1w, const void* d1b,
                                             const int* __restrict__ batch,
                                             unsigned* __restrict__ gmax, int* __restrict__ npg) {
  int d = blockIdx.x, tid = threadIdx.x;
  int base = rowptr[d];
  int deg = rowptr[d + 1] - base;
  __shared__ float lm[4], lsi[4], os[HC];
  if (tid < 64) {
    int head = tid & 3, slot = tid >> 2;
    float m = -1e30f;
    for (int i = slot; i < deg; i += 16) m = fmaxf(m, p_logit[(size_t)(base + i) * 4 + head]);
#pragma unroll
    for (int st = 4; st < 64; st <<= 1) m = fmaxf(m, __shfl_xor(m, st, 64));
    float s = 0.f;
    for (int i = slot; i < deg; i += 16) s += __expf(p_logit[(size_t)(base + i) * 4 + head] - m);
#pragma unroll
    for (int st = 4; st < 64; st <<= 1) s += __shfl_xor(s, st, 64);
    if (tid < 4) { lm[tid] = m; lsi[tid] = (deg > 0) ? 1.f / s : 0.f; }
  }
  __syncthreads();
  int j = tid, head = j >> 5;
  float m = lm[head], si = lsi[head];
  float acc = 0.f;
  for (int i = 0; i < deg; ++i) {
    unsigned sp = csr[base + i];
    int src = sp & 0xFFFFF;
    float alpha = __expf(p_logit[(size_t)(base + i) * 4 + head] - m) * si;
    acc += bf2f(h[(size_t)src * HC + j]) * alpha;
  }
  os[j] = lrelu(acc + ldf<BF>(gbias, j), 0.01f);
  __syncthreads();
  if (j < 16) {
    float a2 = ldf<BF>(d1b, j);
#pragma unroll
    for (int k = 0; k < HC; ++k) a2 += os[k] * ldf<BF>(d1w, (size_t)k * 16 + j);
    a2 = lrelu(a2, 0.01f);
    atomicMax(&gmax[batch[d] * 16 + j], fenc(a2));
  }
  if (j == 0) atomicAdd(&npg[batch[d]], 1);
}
__global__ void k_gat_agg(const int* rowptr, const unsigned* csr, const float* p_logit,
                          const bf16* h, const void* gbias, const void* d1w, const void* d1b,
                          const int* batch, unsigned* gmax, int* npg, const int* flag) {
  if (__builtin_amdgcn_readfirstlane(*flag))
    gat_agg_body<true>(rowptr, csr, p_logit, h, gbias, d1w, d1b, batch, gmax, npg);
  else
    gat_agg_body<false>(rowptr, csr, p_logit, h, gbias, d1w, d1b, batch, gmax, npg);
}

// ---- RGCN1: xw1[r,n,32] = x[n] @ rw1[r] ----
template<bool BF>
__device__ __forceinline__ void xw1_body(const void* x, const void* rw1, bf16* __restrict__ xw1) {
  __shared__ float xs[8][F_IN];
  int tid = threadIdx.x;
  int n0 = blockIdx.x * 8;
  for (int i = tid; i < 8 * F_IN; i += 256) {
    int nn = n0 + (i >> 6);
    xs[i >> 6][i & 63] = (nn < N_NODES) ? ldf<BF>(x, (size_t)nn * F_IN + (i & 63)) : 0.f;
  }
  __syncthreads();
  int nl = tid >> 5, c = tid & 31;
  int n = n0 + nl, r = blockIdx.y;
  float acc = 0.f;
#pragma unroll
  for (int k = 0; k < F_IN; ++k) acc += xs[nl][k] * ldf<BF>(rw1, (size_t)(r * F_IN + k) * 32 + c);
  if (n < N_NODES) xw1[((size_t)r * N_NODES + n) * 32 + c] = f2bf(acc);
}
__global__ void k_xw1(const void* x, const void* rw1, bf16* xw1, const int* flag) {
  if (__builtin_amdgcn_readfirstlane(*flag)) xw1_body<true>(x, rw1, xw1);
  else xw1_body<false>(x, rw1, xw1);
}

// ---- RGCN1 gather + root + relu -> z1 (8 nodes x 32 ch per 256-block) ----
template<bool BF>
__device__ __forceinline__ void ragg1_body(const int* __restrict__ rowptr,
                                           const unsigned* __restrict__ csr,
                                           const int* __restrict__ cnt,
                                           const bf16* __restrict__ xw1, const void* x,
                                           const void* root1, const void* rb1,
                                           float* __restrict__ z1) {
  __shared__ float xs[8][F_IN];
  __shared__ float cinv[8][N_REL];
  int tid = threadIdx.x;
  int n0 = blockIdx.x * 8;
  for (int i = tid; i < 8 * F_IN; i += 256) {
    int nn = n0 + (i >> 6);
    xs[i >> 6][i & 63] = (nn < N_NODES) ? ldf<BF>(x, (size_t)nn * F_IN + (i & 63)) : 0.f;
  }
  if (tid < 64) {
    int nn = n0 + (tid >> 3), rel = tid & 7;
    int cv = (nn < N_NODES) ? cnt[nn * N_REL + rel] : 0;
    cinv[tid >> 3][rel] = (cv > 0) ? 1.f / (float)cv : 0.f;
  }
  __syncthreads();
  int nl = tid >> 5, c = tid & 31;
  int n = n0 + nl;
  if (n >= N_NODES) return;
  int base = rowptr[n], deg = rowptr[n + 1] - base;
  float acc = 0.f;
  for (int i = 0; i < deg; ++i) {
    unsigned sp = csr[base + i];
    int src = sp & 0xFFFFF, t = sp >> 20;
    acc += bf2f(xw1[((size_t)t * N_NODES + src) * 32 + c]) * cinv[nl][t];
  }
  float r = 0.f;
#pragma unroll
  for (int k = 0; k < F_IN; ++k) r += xs[nl][k] * ldf<BF>(root1, (size_t)k * 32 + c);
  z1[(size_t)n * 32 + c] = fmaxf(acc + r + ldf<BF>(rb1, c), 0.f);
}
__global__ void k_ragg1(const int* rowptr, const unsigned* csr, const int* cnt,
                        const bf16* xw1, const void* x, const void* root1, const void* rb1,
                        float* z1, const int* flag) {
  if (__builtin_amdgcn_readfirstlane(*flag))
    ragg1_body<true>(rowptr, csr, cnt, xw1, x, root1, rb1, z1);
  else
    ragg1_body<false>(rowptr, csr, cnt, xw1, x, root1, rb1, z1);
}

// ---- RGCN2: zw2[r,n,16] = z1[n] @ rw2[r] ----
template<bool BF>
__device__ __forceinline__ void zw2_body(const float* __restrict__ z1, const void* rw2,
                                         bf16* __restrict__ zw2) {
  __shared__ float zs[16][32];
  int tid = threadIdx.x;
  int n0 = blockIdx.x * 16;
  for (int i = tid; i < 16 * 32; i += 256) {
    int nn = n0 + (i >> 5);
    zs[i >> 5][i & 31] = (nn < N_NODES) ? z1[(size_t)nn * 32 + (i & 31)] : 0.f;
  }
  __syncthreads();
  int nl = tid >> 4, c = tid & 15;
  int n = n0 + nl, r = blockIdx.y;
  float acc = 0.f;
#pragma unroll
  for (int k = 0; k < 32; ++k) acc += zs[nl][k] * ldf<BF>(rw2, (size_t)(r * 32 + k) * 16 + c);
  if (n < N_NODES) zw2[((size_t)r * N_NODES + n) * 16 + c] = f2bf(acc);
}
__global__ void k_zw2(const float* z1, const void* rw2, bf16* zw2, const int* flag) {
  if (__builtin_amdgcn_readfirstlane(*flag)) zw2_body<true>(z1, rw2, zw2);
  else zw2_body<false>(z1, rw2, zw2);
}

// ---- RGCN2 gather + root + relu + graph-sum (16 nodes x 16 ch per 256-block) ----
template<bool BF>
__device__ __forceinline__ void ragg2_body(const int* __restrict__ rowptr,
                                           const unsigned* __restrict__ csr,
                                           const int* __restrict__ cnt,
                                           const bf16* __restrict__ zw2,
                                           const float* __restrict__ z1, const void* root2,
                                           const void* rb2, const int* __restrict__ batch,
                                           float* __restrict__ gsum) {
  __shared__ float zs[16][32];
  __shared__ float cinv[16][N_REL];
  int tid = threadIdx.x;
  int n0 = blockIdx.x * 16;
  for (int i = tid; i < 16 * 32; i += 256) {
    int nn = n0 + (i >> 5);
    zs[i >> 5][i & 31] = (nn < N_NODES) ? z1[(size_t)nn * 32 + (i & 31)] : 0.f;
  }
  if (tid < 128) {
    int nn = n0 + (tid >> 3), rel = tid & 7;
    int cv = (nn < N_NODES) ? cnt[nn * N_REL + rel] : 0;
    cinv[tid >> 3][rel] = (cv > 0) ? 1.f / (float)cv : 0.f;
  }
  __syncthreads();
  int nl = tid >> 4, c = tid & 15;
  int n = n0 + nl;
  if (n >= N_NODES) return;
  int base = rowptr[n], deg = rowptr[n + 1] - base;
  float acc = 0.f;
  for (int i = 0; i < deg; ++i) {
    unsigned sp = csr[base + i];
    int src = sp & 0xFFFFF, t = sp >> 20;
    acc += bf2f(zw2[((size_t)t * N_NODES + src) * 16 + c]) * cinv[nl][t];
  }
  float r = 0.f;
#pragma unroll
  for (int k = 0; k < 32; ++k) r += zs[nl][k] * ldf<BF>(root2, (size_t)k * 16 + c);
  acc = fmaxf(acc + r + ldf<BF>(rb2, c), 0.f);
  atomicAdd(&gsum[batch[n] * 16 + c], acc);
}
__global__ void k_ragg2(const int* rowptr, const unsigned* csr, const int* cnt,
                        const bf16* zw2, const float* z1, const void* root2, const void* rb2,
                        const int* batch, float* gsum, const int* flag) {
  if (__builtin_amdgcn_readfirstlane(*flag))
    ragg2_body<true>(rowptr, csr, cnt, zw2, z1, root2, rb2, batch, gsum);
  else
    ragg2_body<false>(rowptr, csr, cnt, zw2, z1, root2, rb2, batch, gsum);
}

// ---- final: zc = [gmax, gmean] @ dense_w + dense_b ----
template<bool BF>
__device__ __forceinline__ void final_body(const unsigned* __restrict__ gmax,
                                           const float* __restrict__ gsum,
                                           const int* __restrict__ npg, const void* dw,
                                           const void* db, void* out) {
  int g = threadIdx.x;
  if (g >= N_GRAPH) return;
  float acc = ldf<BF>(db, 0);
  int np = npg[g]; if (np < 1) np = 1;
  float inv = 1.f / (float)np;
#pragma unroll
  for (int c = 0; c < 16; ++c) {
    acc += fdec(gmax[g * 16 + c]) * ldf<BF>(dw, c);
    acc += (gsum[g * 16 + c] * inv) * ldf<BF>(dw, 16 + c);
  }
  if (BF) ((bf16*)out)[g] = f2bf(acc);
  else ((float*)out)[g] = acc;
}
__global__ void k_final(const unsigned* gmax, const float* gsum, const int* npg,
                        const void* dw, const void* db, void* out, const int* flag) {
  if (__builtin_amdgcn_readfirstlane(*flag)) final_body<true>(gmax, gsum, npg, dw, db, out);
  else final_body<false>(gmax, gsum, npg, dw, db, out);
}

extern "C" void kernel_launch(void* const* d_in, const int* in_sizes, int n_in,
                              void* d_out, int out_size, void* d_ws, size_t ws_size,
                              hipStream_t stream) {
  const void* x        = d_in[0];
  const int*  ei       = (const int*)d_in[1];
  const int*  etype    = (const int*)d_in[2];
  const int*  batch    = (const int*)d_in[3];
  const void* gat_w    = d_in[4];
  const void* att_src  = d_in[5];
  const void* att_dst  = d_in[6];
  const void* gat_bias = d_in[7];
  const void* d1w      = d_in[8];
  const void* d1b      = d_in[9];
  const void* rw1      = d_in[10];
  const void* root1    = d_in[11];
  const void* rb1      = d_in[12];
  const void* rw2      = d_in[13];
  const void* root2    = d_in[14];
  const void* rb2      = d_in[15];
  const void* dw       = d_in[16];
  const void* db       = d_in[17];

  // ---- workspace layout (~78 MB, phase-aliased region A) ----
  char* ws = (char*)d_ws;
  const size_t o_h     = 0;           // bf16 N*128 (25.6MB)   — GAT
  const size_t o_plog  = 25600000;    // f32  E*4   (25.6MB)   — GAT
  const size_t o_xw1   = 0;           // bf16 R*N*32 (51.2MB)  — RGCN1, overlays h+plog
  const size_t o_zw2   = 0;           // bf16 R*N*16 (25.6MB)  — RGCN2, overlays xw1 (dead)
  const size_t o_asrc  = 51200000;    // f32 N*4 (1.6MB)
  const size_t o_adst  = 52800000;    // f32 N*4 (1.6MB)
  const size_t o_deg   = 54400000;    // i32 N   (0.4MB)
  const size_t o_rowp  = 54800000;    // i32 N+1
  const size_t o_wp    = 55200016;    // i32 N
  const size_t o_cnt   = 55600032;    // i32 N*8 (3.2MB)
  const size_t o_csr   = 58800032;    // u32 E   (6.4MB)
  const size_t o_z1    = 65200032;    // f32 N*32 (12.8MB)
  const size_t o_sblk  = 78000032;    // i32 NBLK_SCAN
  const size_t o_gmax  = 78001600;    // u32 G*16
  const size_t o_gsum  = 78017984;    // f32 G*16
  const size_t o_npg   = 78034368;    // i32 G
  const size_t o_flag  = 78035392;    // i32
  const size_t total   = 78035396;
  if (ws_size < total) return;

  bf16*     h      = (bf16*)(ws + o_h);
  float*    plog   = (float*)(ws + o_plog);
  bf16*     xw1    = (bf16*)(ws + o_xw1);
  bf16*     zw2    = (bf16*)(ws + o_zw2);
  float*    a_src  = (float*)(ws + o_asrc);
  float*    a_dst  = (float*)(ws + o_adst);
  int*      deg    = (int*)(ws + o_deg);
  int*      rowptr = (int*)(ws + o_rowp);
  int*      wp     = (int*)(ws + o_wp);
  int*      cnt    = (int*)(ws + o_cnt);
  unsigned* csr    = (unsigned*)(ws + o_csr);
  float*    z1     = (float*)(ws + o_z1);
  int*      sblk   = (int*)(ws + o_sblk);
  unsigned* gmax   = (unsigned*)(ws + o_gmax);
  float*    gsum   = (float*)(ws + o_gsum);
  int*      npg    = (int*)(ws + o_npg);
  int*      flag   = (int*)(ws + o_flag);

  // dtype probe
  k_probe<<<1, 256, 0, stream>>>((const u16*)x, flag);

  // zero-init: deg..cnt contiguous block, and gmax/gsum/npg
  hipMemsetAsync(ws + o_deg, 0, o_csr - o_deg, stream);
  hipMemsetAsync(ws + o_gmax, 0, 33792, stream);

  // node transform + attention coefficients (independent of CSR)
  k_gat_h<<<N_NODES, 128, 0, stream>>>(x, gat_w, att_src, att_dst, h, a_src, a_dst, flag);

  // CSR build
  k_hist<<<(N_EDGES + 255) / 256, 256, 0, stream>>>(ei, etype, deg, cnt);
  k_scan_a<<<NBLK_SCAN, 256, 0, stream>>>(deg, rowptr, sblk);
  k_scan_b<<<1, 512, 0, stream>>>(sblk);
  k_scan_c<<<NBLK_SCAN, 256, 0, stream>>>(rowptr, wp, sblk);
  k_scatter<<<(N_EDGES + 255) / 256, 256, 0, stream>>>(ei, etype, a_src, a_dst, wp, csr,
                                                       (float4*)plog);

  // GAT aggregate (gather) + epilogue fused
  k_gat_agg<<<N_NODES, 128, 0, stream>>>(rowptr, csr, plog, h, gat_bias, d1w, d1b, batch,
                                         gmax, npg, flag);

  // RGCN layer 1 (xw1 overlays h+plog — GAT phase done)
  k_xw1<<<dim3((N_NODES + 7) / 8, N_REL), 256, 0, stream>>>(x, rw1, xw1, flag);
  k_ragg1<<<(N_NODES + 7) / 8, 256, 0, stream>>>(rowptr, csr, cnt, xw1, x, root1, rb1, z1, flag);

  // RGCN layer 2 (zw2 overlays xw1 — layer-1 gather done)
  k_zw2<<<dim3((N_NODES + 15) / 16, N_REL), 256, 0, stream>>>(z1, rw2, zw2, flag);
  k_ragg2<<<(N_NODES + 15) / 16, 256, 0, stream>>>(rowptr, csr, cnt, zw2, z1, root2, rb2,
                                                   batch, gsum, flag);

  // fuse
  k_final<<<1, 256, 0, stream>>>(gmax, gsum, npg, dw, db, d_out, flag);
}

// Round 4
// 1314.760 us; speedup vs baseline: 2.0191x; 1.0917x over previous
//
#include <hip/hip_runtime.h>
#include <hip/hip_bf16.h>

typedef __hip_bfloat16 bf16;
typedef unsigned short u16;

#define N_NODES 100000
#define N_EDGES 1600000
#define F_IN 64
#define N_REL 8
#define N_GRAPH 256
#define N_HEAD 4
#define HC 128          // H*C
#define NBLK_SCAN 391   // ceil(100000/256)

__device__ __forceinline__ float lrelu(float x, float s) { return x >= 0.f ? x : s * x; }
__device__ __forceinline__ unsigned fenc(float f) {
  unsigned b = __float_as_uint(f);
  return (b & 0x80000000u) ? ~b : (b | 0x80000000u);
}
__device__ __forceinline__ float fdec(unsigned u) {
  float v = __uint_as_float((u & 0x80000000u) ? (u & 0x7fffffffu) : ~u);
  return fmaxf(fminf(v, 3e38f), -3e38f);
}
__device__ __forceinline__ float bf2f(bf16 v) { return __bfloat162float(v); }
__device__ __forceinline__ bf16 f2bf(float v) { return __float2bfloat16(v); }
__device__ __forceinline__ float lo_bf(unsigned u) { return __uint_as_float(u << 16); }
__device__ __forceinline__ float hi_bf(unsigned u) { return __uint_as_float(u & 0xFFFF0000u); }

// dtype-adaptive load: BF=true -> bf16 array; BF=false -> fp32 array
template<bool BF> __device__ __forceinline__ float ldf(const void* p, size_t i) {
  if (BF) { u16 v = ((const u16*)p)[i]; return __uint_as_float(((unsigned)v) << 16); }
  else    { return ((const float*)p)[i]; }
}

// ---- dtype probe ----
__global__ void k_probe(const u16* __restrict__ xr, int* __restrict__ flag) {
  int t = threadIdx.x;
  int c = 0;
  for (int i = t; i < 1024; i += 256) {
    unsigned e = (xr[i] >> 7) & 0xFFu;
    if (e >= 100u && e <= 140u) c++;
  }
  __shared__ int sc[256];
  sc[t] = c;
  __syncthreads();
  for (int s = 128; s; s >>= 1) { if (t < s) sc[t] += sc[t + s]; __syncthreads(); }
  if (t == 0) *flag = (sc[0] >= 800) ? 1 : 0;
}

// ---- GAT: h = x @ gat_w ; a_src/a_dst rowwise head-dots ----
template<bool BF>
__device__ __forceinline__ void gat_h_body(const void* x, const void* w, const void* att_s,
                                           const void* att_d, bf16* __restrict__ h,
                                           float* __restrict__ a_src, float* __restrict__ a_dst) {
  int n = blockIdx.x, j = threadIdx.x;
  __shared__ float xs[F_IN];
  if (j < F_IN) xs[j] = ldf<BF>(x, (size_t)n * F_IN + j);
  __syncthreads();
  float acc = 0.f;
#pragma unroll
  for (int k = 0; k < F_IN; ++k) acc += xs[k] * ldf<BF>(w, (size_t)k * HC + j);
  h[(size_t)n * HC + j] = f2bf(acc);
  float ps = acc * ldf<BF>(att_s, j);
  float pd = acc * ldf<BF>(att_d, j);
#pragma unroll
  for (int off = 16; off > 0; off >>= 1) {
    ps += __shfl_down(ps, off, 32);
    pd += __shfl_down(pd, off, 32);
  }
  if ((j & 31) == 0) {
    a_src[n * N_HEAD + (j >> 5)] = ps;
    a_dst[n * N_HEAD + (j >> 5)] = pd;
  }
}
__global__ void k_gat_h(const void* x, const void* w, const void* att_s, const void* att_d,
                        bf16* h, float* a_src, float* a_dst, const int* flag) {
  if (__builtin_amdgcn_readfirstlane(*flag)) gat_h_body<true>(x, w, att_s, att_d, h, a_src, a_dst);
  else gat_h_body<false>(x, w, att_s, att_d, h, a_src, a_dst);
}

// ---- CSR build: histogram ----
__global__ void k_hist(const int* __restrict__ ei, const int* __restrict__ etype,
                       int* __restrict__ deg, int* __restrict__ cnt) {
  int e = blockIdx.x * 256 + threadIdx.x;
  if (e >= N_EDGES) return;
  int d = ei[N_EDGES + e], t = etype[e];
  atomicAdd(&deg[d], 1);
  atomicAdd(&cnt[d * N_REL + t], 1);
}

// ---- 2-level exclusive scan ----
__global__ void k_scan_a(const int* __restrict__ deg, int* __restrict__ rowptr,
                         int* __restrict__ scanblk) {
  __shared__ int buf[256];
  int tid = threadIdx.x;
  int i = blockIdx.x * 256 + tid;
  int v = (i < N_NODES) ? deg[i] : 0;
  buf[tid] = v;
  __syncthreads();
  for (int st = 1; st < 256; st <<= 1) {
    int t = buf[tid];
    int a = (tid >= st) ? buf[tid - st] : 0;
    __syncthreads();
    buf[tid] = t + a;
    __syncthreads();
  }
  if (i < N_NODES) rowptr[i] = buf[tid] - v;
  if (tid == 255) scanblk[blockIdx.x] = buf[255];
}
__global__ void k_scan_b(int* __restrict__ scanblk) {
  __shared__ int buf[512];
  int tid = threadIdx.x;
  int v = (tid < NBLK_SCAN) ? scanblk[tid] : 0;
  buf[tid] = v;
  __syncthreads();
  for (int st = 1; st < 512; st <<= 1) {
    int t = buf[tid];
    int a = (tid >= st) ? buf[tid - st] : 0;
    __syncthreads();
    buf[tid] = t + a;
    __syncthreads();
  }
  if (tid < NBLK_SCAN) scanblk[tid] = buf[tid] - v;
}
__global__ void k_scan_c(int* __restrict__ rowptr, int* __restrict__ wp,
                         const int* __restrict__ scanblk) {
  int i = blockIdx.x * 256 + threadIdx.x;
  if (i < N_NODES) {
    int val = rowptr[i] + scanblk[blockIdx.x];
    rowptr[i] = val;
    wp[i] = val;
  } else if (i == N_NODES) {
    rowptr[N_NODES] = N_EDGES;
  }
}

// ---- scatter edges into CSR order; store attention logits per pos ----
__global__ void k_scatter(const int* __restrict__ ei, const int* __restrict__ etype,
                          const float* __restrict__ a_src, const float* __restrict__ a_dst,
                          int* __restrict__ wp, unsigned* __restrict__ csr,
                          float4* __restrict__ p_logit) {
  int e = blockIdx.x * 256 + threadIdx.x;
  if (e >= N_EDGES) return;
  int sn = ei[e], d = ei[N_EDGES + e], t = etype[e];
  int pos = atomicAdd(&wp[d], 1);
  csr[pos] = (unsigned)sn | ((unsigned)t << 20);
  const float4 as = *(const float4*)&a_src[sn * 4];
  const float4 ad = *(const float4*)&a_dst[d * 4];
  float4 lg;
  lg.x = lrelu(as.x + ad.x, 0.2f);
  lg.y = lrelu(as.y + ad.y, 0.2f);
  lg.z = lrelu(as.z + ad.z, 0.2f);
  lg.w = lrelu(as.w + ad.w, 0.2f);
  p_logit[pos] = lg;
}

// ---- GAT aggregate: 4 nodes/block, 1 wave/node, 2ch per lane, unroll x4 ----
template<bool BF>
__device__ __forceinline__ void gat_agg_body(const int* __restrict__ rowptr,
                                             const unsigned* __restrict__ csr,
                                             const float* __restrict__ p_logit,
                                             const unsigned* __restrict__ hu, const void* gbias,
                                             const void* d1w, const void* d1b,
                                             const int* __restrict__ batch,
                                             unsigned* __restrict__ gmax, int* __restrict__ npg) {
  int tid = threadIdx.x;
  int wave = tid >> 6, l = tid & 63;
  int d = blockIdx.x * 4 + wave;  // grid = 25000, exact
  __shared__ float os[4][132];
  int base = rowptr[d];
  int deg = rowptr[d + 1] - base;
  int head = l >> 4, slot = l & 15;
  // segment softmax m, s (per-wave, 16-lane butterflies)
  float m = -1e30f;
  for (int i = slot; i < deg; i += 16) m = fmaxf(m, p_logit[(size_t)(base + i) * 4 + head]);
#pragma unroll
  for (int st = 1; st < 16; st <<= 1) m = fmaxf(m, __shfl_xor(m, st, 64));
  float s = 0.f;
  for (int i = slot; i < deg; i += 16) s += __expf(p_logit[(size_t)(base + i) * 4 + head] - m);
#pragma unroll
  for (int st = 1; st < 16; st <<= 1) s += __shfl_xor(s, st, 64);
  float si = (deg > 0) ? 1.f / s : 0.f;
  // gather: lane covers channels 2l, 2l+1 (one u32 = 2 bf16); unroll x4 for MLP
  float acc0 = 0.f, acc1 = 0.f;
  int i = 0;
  for (; i + 4 <= deg; i += 4) {
    unsigned sp0 = csr[base + i], sp1 = csr[base + i + 1];
    unsigned sp2 = csr[base + i + 2], sp3 = csr[base + i + 3];
    float e0 = __expf(p_logit[(size_t)(base + i) * 4 + head] - m);
    float e1 = __expf(p_logit[(size_t)(base + i + 1) * 4 + head] - m);
    float e2 = __expf(p_logit[(size_t)(base + i + 2) * 4 + head] - m);
    float e3 = __expf(p_logit[(size_t)(base + i + 3) * 4 + head] - m);
    unsigned h0 = hu[(size_t)(sp0 & 0xFFFFF) * 64 + l];
    unsigned h1 = hu[(size_t)(sp1 & 0xFFFFF) * 64 + l];
    unsigned h2 = hu[(size_t)(sp2 & 0xFFFFF) * 64 + l];
    unsigned h3 = hu[(size_t)(sp3 & 0xFFFFF) * 64 + l];
    acc0 += lo_bf(h0) * e0 + lo_bf(h1) * e1 + lo_bf(h2) * e2 + lo_bf(h3) * e3;
    acc1 += hi_bf(h0) * e0 + hi_bf(h1) * e1 + hi_bf(h2) * e2 + hi_bf(h3) * e3;
  }
  for (; i < deg; ++i) {
    unsigned sp = csr[base + i];
    float e0 = __expf(p_logit[(size_t)(base + i) * 4 + head] - m);
    unsigned h0 = hu[(size_t)(sp & 0xFFFFF) * 64 + l];
    acc0 += lo_bf(h0) * e0;
    acc1 += hi_bf(h0) * e0;
  }
  acc0 *= si; acc1 *= si;
  os[wave][2 * l]     = lrelu(acc0 + ldf<BF>(gbias, 2 * l), 0.01f);
  os[wave][2 * l + 1] = lrelu(acc1 + ldf<BF>(gbias, 2 * l + 1), 0.01f);
  __syncthreads();
  if (tid < 64) {
    int node = tid >> 4, out = tid & 15;
    float a2 = ldf<BF>(d1b, out);
#pragma unroll
    for (int k = 0; k < HC; ++k) a2 += os[node][k] * ldf<BF>(d1w, (size_t)k * 16 + out);
    a2 = lrelu(a2, 0.01f);
    atomicMax(&gmax[batch[blockIdx.x * 4 + node] * 16 + out], fenc(a2));
  }
  if (tid < 4) atomicAdd(&npg[batch[blockIdx.x * 4 + tid]], 1);
}
__global__ void k_gat_agg(const int* rowptr, const unsigned* csr, const float* p_logit,
                          const bf16* h, const void* gbias, const void* d1w, const void* d1b,
                          const int* batch, unsigned* gmax, int* npg, const int* flag) {
  if (__builtin_amdgcn_readfirstlane(*flag))
    gat_agg_body<true>(rowptr, csr, p_logit, (const unsigned*)h, gbias, d1w, d1b, batch, gmax, npg);
  else
    gat_agg_body<false>(rowptr, csr, p_logit, (const unsigned*)h, gbias, d1w, d1b, batch, gmax, npg);
}

// ---- RGCN1: xw1[r,n,32] = x[n] @ rw1[r] ----
template<bool BF>
__device__ __forceinline__ void xw1_body(const void* x, const void* rw1, bf16* __restrict__ xw1) {
  __shared__ float xs[8][F_IN];
  int tid = threadIdx.x;
  int n0 = blockIdx.x * 8;
  for (int i = tid; i < 8 * F_IN; i += 256) {
    int nn = n0 + (i >> 6);
    xs[i >> 6][i & 63] = (nn < N_NODES) ? ldf<BF>(x, (size_t)nn * F_IN + (i & 63)) : 0.f;
  }
  __syncthreads();
  int nl = tid >> 5, c = tid & 31;
  int n = n0 + nl, r = blockIdx.y;
  float acc = 0.f;
#pragma unroll
  for (int k = 0; k < F_IN; ++k) acc += xs[nl][k] * ldf<BF>(rw1, (size_t)(r * F_IN + k) * 32 + c);
  if (n < N_NODES) xw1[((size_t)r * N_NODES + n) * 32 + c] = f2bf(acc);
}
__global__ void k_xw1(const void* x, const void* rw1, bf16* xw1, const int* flag) {
  if (__builtin_amdgcn_readfirstlane(*flag)) xw1_body<true>(x, rw1, xw1);
  else xw1_body<false>(x, rw1, xw1);
}

// ---- RGCN1 gather: 4 nodes/block, 64 lanes = 2 edge-slots x 32 ch, unroll x2 ----
template<bool BF>
__device__ __forceinline__ void ragg1_body(const int* __restrict__ rowptr,
                                           const unsigned* __restrict__ csr,
                                           const int* __restrict__ cnt,
                                           const u16* __restrict__ xw, const void* x,
                                           const void* root1, const void* rb1,
                                           float* __restrict__ z1) {
  __shared__ float xs[4][F_IN];
  __shared__ float cinv[4][N_REL];
  int tid = threadIdx.x;
  int n0 = blockIdx.x * 4;  // grid = 25000, exact
  {
    int nn = n0 + (tid >> 6);
    xs[tid >> 6][tid & 63] = ldf<BF>(x, (size_t)nn * F_IN + (tid & 63));
  }
  if (tid < 32) {
    int cv = cnt[(n0 + (tid >> 3)) * N_REL + (tid & 7)];
    cinv[tid >> 3][tid & 7] = (cv > 0) ? 1.f / (float)cv : 0.f;
  }
  __syncthreads();
  int wave = tid >> 6, l = tid & 63;
  int half = l >> 5, c = l & 31;
  int n = n0 + wave;
  int base = rowptr[n], deg = rowptr[n + 1] - base;
  float acc = 0.f;
  int i = half;
  for (; i + 2 < deg; i += 4) {  // edges i and i+2 per half -> 4 in flight
    unsigned sp0 = csr[base + i], sp1 = csr[base + i + 2];
    int t0 = sp0 >> 20, t1 = sp1 >> 20;
    u16 v0 = xw[((size_t)t0 * N_NODES + (sp0 & 0xFFFFF)) * 32 + c];
    u16 v1 = xw[((size_t)t1 * N_NODES + (sp1 & 0xFFFFF)) * 32 + c];
    acc += __uint_as_float(((unsigned)v0) << 16) * cinv[wave][t0];
    acc += __uint_as_float(((unsigned)v1) << 16) * cinv[wave][t1];
  }
  if (i < deg) {
    unsigned sp = csr[base + i];
    int t = sp >> 20;
    u16 v = xw[((size_t)t * N_NODES + (sp & 0xFFFFF)) * 32 + c];
    acc += __uint_as_float(((unsigned)v) << 16) * cinv[wave][t];
  }
  // root part: half h covers k in [h*32, h*32+32)
  float r = 0.f;
#pragma unroll
  for (int kk = 0; kk < 32; ++kk) {
    int k = half * 32 + kk;
    r += xs[wave][k] * ldf<BF>(root1, (size_t)k * 32 + c);
  }
  float tot = acc + r;
  tot += __shfl_xor(tot, 32, 64);
  if (half == 0) z1[(size_t)n * 32 + c] = fmaxf(tot + ldf<BF>(rb1, c), 0.f);
}
__global__ void k_ragg1(const int* rowptr, const unsigned* csr, const int* cnt,
                        const bf16* xw1, const void* x, const void* root1, const void* rb1,
                        float* z1, const int* flag) {
  if (__builtin_amdgcn_readfirstlane(*flag))
    ragg1_body<true>(rowptr, csr, cnt, (const u16*)xw1, x, root1, rb1, z1);
  else
    ragg1_body<false>(rowptr, csr, cnt, (const u16*)xw1, x, root1, rb1, z1);
}

// ---- RGCN2: zw2[r,n,16] = z1[n] @ rw2[r] ----
template<bool BF>
__device__ __forceinline__ void zw2_body(const float* __restrict__ z1, const void* rw2,
                                         bf16* __restrict__ zw2) {
  __shared__ float zs[16][32];
  int tid = threadIdx.x;
  int n0 = blockIdx.x * 16;
  for (int i = tid; i < 16 * 32; i += 256) {
    int nn = n0 + (i >> 5);
    zs[i >> 5][i & 31] = (nn < N_NODES) ? z1[(size_t)nn * 32 + (i & 31)] : 0.f;
  }
  __syncthreads();
  int nl = tid >> 4, c = tid & 15;
  int n = n0 + nl, r = blockIdx.y;
  float acc = 0.f;
#pragma unroll
  for (int k = 0; k < 32; ++k) acc += zs[nl][k] * ldf<BF>(rw2, (size_t)(r * 32 + k) * 16 + c);
  if (n < N_NODES) zw2[((size_t)r * N_NODES + n) * 16 + c] = f2bf(acc);
}
__global__ void k_zw2(const float* z1, const void* rw2, bf16* zw2, const int* flag) {
  if (__builtin_amdgcn_readfirstlane(*flag)) zw2_body<true>(z1, rw2, zw2);
  else zw2_body<false>(z1, rw2, zw2);
}

// ---- RGCN2 gather: 4 nodes/block, 64 lanes = 4 edge-slots x 16 ch, unroll x2 ----
template<bool BF>
__device__ __forceinline__ void ragg2_body(const int* __restrict__ rowptr,
                                           const unsigned* __restrict__ csr,
                                           const int* __restrict__ cnt,
                                           const u16* __restrict__ zw,
                                           const float* __restrict__ z1, const void* root2,
                                           const void* rb2, const int* __restrict__ batch,
                                           float* __restrict__ gsum) {
  __shared__ float zs[4][33];
  __shared__ float cinv[4][N_REL];
  int tid = threadIdx.x;
  int n0 = blockIdx.x * 4;  // grid = 25000, exact
  if (tid < 128) {
    int nn = n0 + (tid >> 5);
    zs[tid >> 5][tid & 31] = z1[(size_t)nn * 32 + (tid & 31)];
  }
  if (tid < 32) {
    int cv = cnt[(n0 + (tid >> 3)) * N_REL + (tid & 7)];
    cinv[tid >> 3][tid & 7] = (cv > 0) ? 1.f / (float)cv : 0.f;
  }
  __syncthreads();
  int wave = tid >> 6, l = tid & 63;
  int q = l >> 4, c = l & 15;
  int n = n0 + wave;
  int base = rowptr[n], deg = rowptr[n + 1] - base;
  float acc = 0.f;
  int i = q;
  for (; i + 4 < deg; i += 8) {  // edges i, i+4 per quarter -> 8 in flight
    unsigned sp0 = csr[base + i], sp1 = csr[base + i + 4];
    int t0 = sp0 >> 20, t1 = sp1 >> 20;
    u16 v0 = zw[((size_t)t0 * N_NODES + (sp0 & 0xFFFFF)) * 16 + c];
    u16 v1 = zw[((size_t)t1 * N_NODES + (sp1 & 0xFFFFF)) * 16 + c];
    acc += __uint_as_float(((unsigned)v0) << 16) * cinv[wave][t0];
    acc += __uint_as_float(((unsigned)v1) << 16) * cinv[wave][t1];
  }
  if (i < deg) {
    unsigned sp = csr[base + i];
    int t = sp >> 20;
    u16 v = zw[((size_t)t * N_NODES + (sp & 0xFFFFF)) * 16 + c];
    acc += __uint_as_float(((unsigned)v) << 16) * cinv[wave][t];
  }
  // root part: quarter q covers k in [q*8, q*8+8)
  float r = 0.f;
#pragma unroll
  for (int kk = 0; kk < 8; ++kk) {
    int k = q * 8 + kk;
    r += zs[wave][k] * ldf<BF>(root2, (size_t)k * 16 + c);
  }
  float tot = acc + r;
  tot += __shfl_xor(tot, 16, 64);
  tot += __shfl_xor(tot, 32, 64);
  if (q == 0) {
    float z2 = fmaxf(tot + ldf<BF>(rb2, c), 0.f);
    atomicAdd(&gsum[batch[n] * 16 + c], z2);
  }
}
__global__ void k_ragg2(const int* rowptr, const unsigned* csr, const int* cnt,
                        const bf16* zw2, const float* z1, const void* root2, const void* rb2,
                        const int* batch, float* gsum, const int* flag) {
  if (__builtin_amdgcn_readfirstlane(*flag))
    ragg2_body<true>(rowptr, csr, cnt, (const u16*)zw2, z1, root2, rb2, batch, gsum);
  else
    ragg2_body<false>(rowptr, csr, cnt, (const u16*)zw2, z1, root2, rb2, batch, gsum);
}

// ---- final ----
template<bool BF>
__device__ __forceinline__ void final_body(const unsigned* __restrict__ gmax,
                                           const float* __restrict__ gsum,
                                           const int* __restrict__ npg, const void* dw,
                                           const void* db, void* out) {
  int g = threadIdx.x;
  if (g >= N_GRAPH) return;
  float acc = ldf<BF>(db, 0);
  int np = npg[g]; if (np < 1) np = 1;
  float inv = 1.f / (float)np;
#pragma unroll
  for (int c = 0; c < 16; ++c) {
    acc += fdec(gmax[g * 16 + c]) * ldf<BF>(dw, c);
    acc += (gsum[g * 16 + c] * inv) * ldf<BF>(dw, 16 + c);
  }
  if (BF) ((bf16*)out)[g] = f2bf(acc);
  else ((float*)out)[g] = acc;
}
__global__ void k_final(const unsigned* gmax, const float* gsum, const int* npg,
                        const void* dw, const void* db, void* out, const int* flag) {
  if (__builtin_amdgcn_readfirstlane(*flag)) final_body<true>(gmax, gsum, npg, dw, db, out);
  else final_body<false>(gmax, gsum, npg, dw, db, out);
}

extern "C" void kernel_launch(void* const* d_in, const int* in_sizes, int n_in,
                              void* d_out, int out_size, void* d_ws, size_t ws_size,
                              hipStream_t stream) {
  const void* x        = d_in[0];
  const int*  ei       = (const int*)d_in[1];
  const int*  etype    = (const int*)d_in[2];
  const int*  batch    = (const int*)d_in[3];
  const void* gat_w    = d_in[4];
  const void* att_src  = d_in[5];
  const void* att_dst  = d_in[6];
  const void* gat_bias = d_in[7];
  const void* d1w      = d_in[8];
  const void* d1b      = d_in[9];
  const void* rw1      = d_in[10];
  const void* root1    = d_in[11];
  const void* rb1      = d_in[12];
  const void* rw2      = d_in[13];
  const void* root2    = d_in[14];
  const void* rb2      = d_in[15];
  const void* dw       = d_in[16];
  const void* db       = d_in[17];

  // ---- workspace layout (~78 MB, phase-aliased region A) ----
  char* ws = (char*)d_ws;
  const size_t o_h     = 0;           // bf16 N*128 (25.6MB)   — GAT
  const size_t o_plog  = 25600000;    // f32  E*4   (25.6MB)   — GAT
  const size_t o_xw1   = 0;           // bf16 R*N*32 (51.2MB)  — RGCN1, overlays h+plog
  const size_t o_zw2   = 0;           // bf16 R*N*16 (25.6MB)  — RGCN2, overlays xw1 (dead)
  const size_t o_asrc  = 51200000;    // f32 N*4 (1.6MB)
  const size_t o_adst  = 52800000;    // f32 N*4 (1.6MB)
  const size_t o_deg   = 54400000;    // i32 N   (0.4MB)
  const size_t o_rowp  = 54800000;    // i32 N+1
  const size_t o_wp    = 55200016;    // i32 N
  const size_t o_cnt   = 55600032;    // i32 N*8 (3.2MB)
  const size_t o_csr   = 58800032;    // u32 E   (6.4MB)
  const size_t o_z1    = 65200032;    // f32 N*32 (12.8MB)
  const size_t o_sblk  = 78000032;    // i32 NBLK_SCAN
  const size_t o_gmax  = 78001600;    // u32 G*16
  const size_t o_gsum  = 78017984;    // f32 G*16
  const size_t o_npg   = 78034368;    // i32 G
  const size_t o_flag  = 78035392;    // i32
  const size_t total   = 78035396;
  if (ws_size < total) return;

  bf16*     h      = (bf16*)(ws + o_h);
  float*    plog   = (float*)(ws + o_plog);
  bf16*     xw1    = (bf16*)(ws + o_xw1);
  bf16*     zw2    = (bf16*)(ws + o_zw2);
  float*    a_src  = (float*)(ws + o_asrc);
  float*    a_dst  = (float*)(ws + o_adst);
  int*      deg    = (int*)(ws + o_deg);
  int*      rowptr = (int*)(ws + o_rowp);
  int*      wp     = (int*)(ws + o_wp);
  int*      cnt    = (int*)(ws + o_cnt);
  unsigned* csr    = (unsigned*)(ws + o_csr);
  float*    z1     = (float*)(ws + o_z1);
  int*      sblk   = (int*)(ws + o_sblk);
  unsigned* gmax   = (unsigned*)(ws + o_gmax);
  float*    gsum   = (float*)(ws + o_gsum);
  int*      npg    = (int*)(ws + o_npg);
  int*      flag   = (int*)(ws + o_flag);

  // dtype probe
  k_probe<<<1, 256, 0, stream>>>((const u16*)x, flag);

  // zero-init: deg..cnt contiguous block, and gmax/gsum/npg
  hipMemsetAsync(ws + o_deg, 0, o_csr - o_deg, stream);
  hipMemsetAsync(ws + o_gmax, 0, 33792, stream);

  // node transform + attention coefficients (independent of CSR)
  k_gat_h<<<N_NODES, 128, 0, stream>>>(x, gat_w, att_src, att_dst, h, a_src, a_dst, flag);

  // CSR build
  k_hist<<<(N_EDGES + 255) / 256, 256, 0, stream>>>(ei, etype, deg, cnt);
  k_scan_a<<<NBLK_SCAN, 256, 0, stream>>>(deg, rowptr, sblk);
  k_scan_b<<<1, 512, 0, stream>>>(sblk);
  k_scan_c<<<NBLK_SCAN, 256, 0, stream>>>(rowptr, wp, sblk);
  k_scatter<<<(N_EDGES + 255) / 256, 256, 0, stream>>>(ei, etype, a_src, a_dst, wp, csr,
                                                       (float4*)plog);

  // GAT aggregate (gather, MLP-unrolled) + epilogue fused
  k_gat_agg<<<N_NODES / 4, 256, 0, stream>>>(rowptr, csr, plog, h, gat_bias, d1w, d1b, batch,
                                             gmax, npg, flag);

  // RGCN layer 1 (xw1 overlays h+plog — GAT phase done)
  k_xw1<<<dim3((N_NODES + 7) / 8, N_REL), 256, 0, stream>>>(x, rw1, xw1, flag);
  k_ragg1<<<N_NODES / 4, 256, 0, stream>>>(rowptr, csr, cnt, xw1, x, root1, rb1, z1, flag);

  // RGCN layer 2 (zw2 overlays xw1 — layer-1 gather done)
  k_zw2<<<dim3((N_NODES + 15) / 16, N_REL), 256, 0, stream>>>(z1, rw2, zw2, flag);
  k_ragg2<<<N_NODES / 4, 256, 0, stream>>>(rowptr, csr, cnt, zw2, z1, root2, rb2,
                                           batch, gsum, flag);

  // fuse
  k_final<<<1, 256, 0, stream>>>(gmax, gsum, npg, dw, db, d_out, flag);
}